// Round 10
// baseline (100.091 us; speedup 1.0000x reference)
//
#include <hip/hip_runtime.h>

#define BATCH 8192
#define NF 1024
#define NS 50000
#define MOM 0.2f
#define MAXOCC 64
#define SENT 0xAAAAAAAAu   // harness poison == our sentinel (>= BATCH as unsigned)

typedef float floatx4 __attribute__((ext_vector_type(4)));

// ---------------------------------------------------------------------------
// k1: 2 unsigned atomicMin per batch slot into a packed uint2 table.
// NO table init needed: poison 0xAAAAAAAA is a valid ">= BATCH" sentinel for
// unsigned min, and fused_bank restores touched entries to SENT afterwards.
__global__ void build_firstlast(const int* __restrict__ labels,
                                uint2* __restrict__ table) {
    const int i = blockIdx.x * blockDim.x + threadIdx.x;
    if (i >= BATCH) return;
    const int y = labels[i];
    atomicMin(&table[y].x, (unsigned)i);                 // first occurrence
    atomicMin(&table[y].y, (unsigned)(BATCH - 1 - i));   // BATCH-1-last
}

// momentum blend + wave-reduced L2 normalize over 16 floats/lane (64 lanes)
__device__ __forceinline__ void blend_normalize(floatx4& v0, floatx4& v1,
                                                floatx4& v2, floatx4& v3,
                                                const floatx4* __restrict__ xrow,
                                                int tid) {
    const float m = MOM, om = 1.0f - MOM;
    const floatx4 x0 = __builtin_nontemporal_load(&xrow[tid]);
    const floatx4 x1 = __builtin_nontemporal_load(&xrow[tid + 64]);
    const floatx4 x2 = __builtin_nontemporal_load(&xrow[tid + 128]);
    const floatx4 x3 = __builtin_nontemporal_load(&xrow[tid + 192]);
    v0 = m * v0 + om * x0;
    v1 = m * v1 + om * x1;
    v2 = m * v2 + om * x2;
    v3 = m * v3 + om * x3;
    float s = v0.x * v0.x + v0.y * v0.y + v0.z * v0.z + v0.w * v0.w
            + v1.x * v1.x + v1.y * v1.y + v1.z * v1.z + v1.w * v1.w
            + v2.x * v2.x + v2.y * v2.y + v2.z * v2.z + v2.w * v2.w
            + v3.x * v3.x + v3.y * v3.y + v3.z * v3.z + v3.w * v3.w;
    for (int off = 32; off; off >>= 1) s += __shfl_xor(s, off, 64);
    const float inv = 1.0f / sqrtf(s);
    v0 *= inv; v1 *= inv; v2 *= inv; v3 *= inv;
}

// ---------------------------------------------------------------------------
// ONE WAVE per bank row: 64 lanes x 4 float4 = 64 B/lane in flight, shuffle-only
// reduction, no LDS/barriers on the copy and single-occurrence paths.
// Untouched rows: NT copy. Verified single occurrence: one blend+normalize.
// Else (true duplicates / garbage table): self-computing path scans labels.
// Touched blocks restore their table entry to SENT (clean for next replay).
__global__ __launch_bounds__(64)
void fused_bank(const float* __restrict__ f_out,
                const float* __restrict__ features,
                const int* __restrict__ labels,
                uint2* __restrict__ table,
                float* __restrict__ out) {
    const int y = blockIdx.x;
    const int tid = threadIdx.x;
    const floatx4* feat4 =
        reinterpret_cast<const floatx4*>(features) + (size_t)y * (NF / 4);
    const floatx4* fout4 = reinterpret_cast<const floatx4*>(f_out);
    floatx4* out4 = reinterpret_cast<floatx4*>(out) + (size_t)y * (NF / 4);

    floatx4 v0 = __builtin_nontemporal_load(&feat4[tid]);
    floatx4 v1 = __builtin_nontemporal_load(&feat4[tid + 64]);
    floatx4 v2 = __builtin_nontemporal_load(&feat4[tid + 128]);
    floatx4 v3 = __builtin_nontemporal_load(&feat4[tid + 192]);

    const uint2 fl = table[y];         // wave-uniform
    const unsigned h = fl.x;
    if (h < BATCH) {
        const unsigned last = BATCH - 1u - fl.y;   // huge if fl.y garbage
        if (h == last && labels[h] == y) {
            // genuine single occurrence (atomicMin gives h<=trueFirst,
            // last>=trueLast, so equality implies exactly one)
            blend_normalize(v0, v1, v2, v3, fout4 + (size_t)h * (NF / 4), tid);
        } else {
            // rare (~600 rows): collect occurrences of y in batch order
            __shared__ int s_cnt;
            __shared__ int s_idx[MAXOCC];
            if (tid == 0) s_cnt = 0;
            __syncthreads();
            for (int j = tid; j < BATCH; j += 64) {
                if (labels[j] == y) {
                    const int p = atomicAdd(&s_cnt, 1);
                    if (p < MAXOCC) s_idx[p] = j;
                }
            }
            __syncthreads();
            const int n = min(s_cnt, MAXOCC);
            if (tid == 0) {            // insertion-sort tiny list ascending
                for (int a = 1; a < n; ++a) {
                    const int key = s_idx[a];
                    int b = a - 1;
                    while (b >= 0 && s_idx[b] > key) { s_idx[b + 1] = s_idx[b]; --b; }
                    s_idx[b + 1] = key;
                }
            }
            __syncthreads();
            for (int t = 0; t < n; ++t)
                blend_normalize(v0, v1, v2, v3,
                                fout4 + (size_t)s_idx[t] * (NF / 4), tid);
        }
        if (tid == 0) table[y] = make_uint2(SENT, SENT);  // self-clean
    }

    __builtin_nontemporal_store(v0, &out4[tid]);
    __builtin_nontemporal_store(v1, &out4[tid + 64]);
    __builtin_nontemporal_store(v2, &out4[tid + 128]);
    __builtin_nontemporal_store(v3, &out4[tid + 192]);
}

extern "C" void kernel_launch(void* const* d_in, const int* in_sizes, int n_in,
                              void* d_out, int out_size, void* d_ws, size_t ws_size,
                              hipStream_t stream) {
    const float* f_out    = (const float*)d_in[0];
    const float* features = (const float*)d_in[1];
    const int*   labels   = (const int*)d_in[2];
    float* out = (float*)d_out;

    uint2* table = (uint2*)d_ws;   // NS x {first, BATCH-1-last}

    build_firstlast<<<(BATCH + 255) / 256, 256, 0, stream>>>(labels, table);
    fused_bank<<<NS, 64, 0, stream>>>(f_out, features, labels, table, out);
}

// Round 11
// 97.210 us; speedup vs baseline: 1.0296x; 1.0296x over previous
//
#include <hip/hip_runtime.h>

#define BATCH 8192
#define NF 1024
#define NS 50000
#define MOM 0.2f
#define SENT 0xAAAAAAAAu   // harness poison == our sentinel (>= BATCH as unsigned)

typedef float floatx4 __attribute__((ext_vector_type(4)));

// ---------------------------------------------------------------------------
// k1: 2 unsigned atomicMin per batch slot into a packed uint2 table.
// NO table init needed: poison 0xAAAAAAAA is a valid ">= BATCH" sentinel for
// unsigned min, and fused_bank restores touched entries to SENT afterwards.
__global__ void build_firstlast(const int* __restrict__ labels,
                                uint2* __restrict__ table) {
    const int i = blockIdx.x * blockDim.x + threadIdx.x;
    if (i >= BATCH) return;
    const int y = labels[i];
    atomicMin(&table[y].x, (unsigned)i);                 // first occurrence
    atomicMin(&table[y].y, (unsigned)(BATCH - 1 - i));   // BATCH-1-last
}

// momentum blend + wave-reduced L2 normalize over 16 floats/lane (64 lanes)
__device__ __forceinline__ void blend_normalize(floatx4& v0, floatx4& v1,
                                                floatx4& v2, floatx4& v3,
                                                const floatx4* __restrict__ xrow,
                                                int lane) {
    const float m = MOM, om = 1.0f - MOM;
    const floatx4 x0 = __builtin_nontemporal_load(&xrow[lane]);
    const floatx4 x1 = __builtin_nontemporal_load(&xrow[lane + 64]);
    const floatx4 x2 = __builtin_nontemporal_load(&xrow[lane + 128]);
    const floatx4 x3 = __builtin_nontemporal_load(&xrow[lane + 192]);
    v0 = m * v0 + om * x0;
    v1 = m * v1 + om * x1;
    v2 = m * v2 + om * x2;
    v3 = m * v3 + om * x3;
    float s = v0.x * v0.x + v0.y * v0.y + v0.z * v0.z + v0.w * v0.w
            + v1.x * v1.x + v1.y * v1.y + v1.z * v1.z + v1.w * v1.w
            + v2.x * v2.x + v2.y * v2.y + v2.z * v2.z + v2.w * v2.w
            + v3.x * v3.x + v3.y * v3.y + v3.z * v3.z + v3.w * v3.w;
    for (int off = 32; off; off >>= 1) s += __shfl_xor(s, off, 64);
    const float inv = 1.0f / sqrtf(s);
    v0 *= inv; v1 *= inv; v2 *= inv; v3 *= inv;
}

// ---------------------------------------------------------------------------
// 256-thread blocks (full occupancy: rounds 3/7/10 showed this is required),
// ONE WAVE PER ROW (4 rows/block): 64 lanes x 4 float4 = 64 B/lane in flight,
// shuffle-only reduction, ZERO LDS, ZERO barriers (waves diverge freely).
// Untouched rows: NT copy. Single occurrence: one blend+normalize.
// Duplicates (~600 rows): ballot-walk the label array in batch order.
// Touched waves restore their table entry to SENT (clean for next replay).
__global__ __launch_bounds__(256)
void fused_bank(const float* __restrict__ f_out,
                const float* __restrict__ features,
                const int* __restrict__ labels,
                uint2* __restrict__ table,
                float* __restrict__ out) {
    const int wave = threadIdx.x >> 6;
    const int lane = threadIdx.x & 63;
    const int y = blockIdx.x * 4 + wave;

    const floatx4* feat4 =
        reinterpret_cast<const floatx4*>(features) + (size_t)y * (NF / 4);
    const floatx4* fout4 = reinterpret_cast<const floatx4*>(f_out);
    floatx4* out4 = reinterpret_cast<floatx4*>(out) + (size_t)y * (NF / 4);

    floatx4 v0 = __builtin_nontemporal_load(&feat4[lane]);
    floatx4 v1 = __builtin_nontemporal_load(&feat4[lane + 64]);
    floatx4 v2 = __builtin_nontemporal_load(&feat4[lane + 128]);
    floatx4 v3 = __builtin_nontemporal_load(&feat4[lane + 192]);

    const uint2 fl = table[y];         // wave-uniform
    const unsigned h = fl.x;
    if (h < BATCH) {
        const unsigned last = BATCH - 1u - fl.y;
        if (h == last && labels[h] == y) {
            // genuine single occurrence (atomicMin from a >=BATCH sentinel
            // makes h==trueFirst, last==trueLast whenever y is present)
            blend_normalize(v0, v1, v2, v3, fout4 + (size_t)h * (NF / 4), lane);
        } else {
            // rare: walk all occurrences of y in batch order via ballot
            for (int base = 0; base < BATCH; base += 64) {
                unsigned long long m = __ballot(labels[base + lane] == y);
                while (m) {
                    const int b = __ffsll(m) - 1;
                    m &= m - 1;
                    blend_normalize(v0, v1, v2, v3,
                                    fout4 + (size_t)(base + b) * (NF / 4), lane);
                }
            }
        }
        if (lane == 0) table[y] = make_uint2(SENT, SENT);  // self-clean
    }

    __builtin_nontemporal_store(v0, &out4[lane]);
    __builtin_nontemporal_store(v1, &out4[lane + 64]);
    __builtin_nontemporal_store(v2, &out4[lane + 128]);
    __builtin_nontemporal_store(v3, &out4[lane + 192]);
}

extern "C" void kernel_launch(void* const* d_in, const int* in_sizes, int n_in,
                              void* d_out, int out_size, void* d_ws, size_t ws_size,
                              hipStream_t stream) {
    const float* f_out    = (const float*)d_in[0];
    const float* features = (const float*)d_in[1];
    const int*   labels   = (const int*)d_in[2];
    float* out = (float*)d_out;

    uint2* table = (uint2*)d_ws;   // NS x {first, BATCH-1-last}

    build_firstlast<<<(BATCH + 255) / 256, 256, 0, stream>>>(labels, table);
    fused_bank<<<NS / 4, 256, 0, stream>>>(f_out, features, labels, table, out);
}

// Round 12
// 81.405 us; speedup vs baseline: 1.2295x; 1.1942x over previous
//
#include <hip/hip_runtime.h>

#define BATCH 8192
#define NF 1024
#define NS 50000
#define MOM 0.2f
#define MAXOCC 64
#define SENT 0xAAAAAAAAu   // harness poison == our sentinel (>= BATCH as unsigned)

typedef float floatx4 __attribute__((ext_vector_type(4)));  // NT-builtin-compatible

// ---------------------------------------------------------------------------
// k1: 2 unsigned atomicMin per batch slot. NO table init needed:
//  - poison 0xAAAAAAAA is a valid ">= BATCH" sentinel for unsigned min
//  - fused_bank restores every touched entry to SENT afterwards
//  - fused_bank is correct for arbitrary table garbage anyway (see guards)
__global__ void build_firstlast(const int* __restrict__ labels,
                                unsigned* __restrict__ first,
                                unsigned* __restrict__ lastm) {
    const int i = blockIdx.x * blockDim.x + threadIdx.x;
    if (i >= BATCH) return;
    const int y = labels[i];
    atomicMin(&first[y], (unsigned)i);
    atomicMin(&lastm[y], (unsigned)(BATCH - 1 - i));
}

// momentum blend + block-reduced L2 normalize (256 threads = 4 waves)
__device__ __forceinline__ void blend_normalize(floatx4& v, const float4 x,
                                                float* s_part, int tid) {
    const float m = MOM, om = 1.0f - MOM;
    v.x = m * v.x + om * x.x;
    v.y = m * v.y + om * x.y;
    v.z = m * v.z + om * x.z;
    v.w = m * v.w + om * x.w;
    float s = v.x * v.x + v.y * v.y + v.z * v.z + v.w * v.w;
    for (int off = 32; off; off >>= 1) s += __shfl_xor(s, off, 64);
    if ((tid & 63) == 0) s_part[tid >> 6] = s;
    __syncthreads();
    const float tot = s_part[0] + s_part[1] + s_part[2] + s_part[3];
    __syncthreads();   // protect s_part before any later reuse
    const float inv = 1.0f / sqrtf(tot);
    v.x *= inv; v.y *= inv; v.z *= inv; v.w *= inv;
}

// ---------------------------------------------------------------------------
// One block per bank row y — block-per-row, 16 B/lane is the empirically
// fastest structure (R9=81.6 vs R3/R7/R10/R11 restructures all >=94).
// Untouched rows: NT streaming copy. Verified single occurrence: one
// blend+normalize. Anything else (true duplicates, or garbage table):
// self-computing path — block scans the 32KB label array, sorts occurrences
// in LDS, applies in batch order. Correct for ANY initial table contents.
// Touched blocks restore their table entries to SENT (self-cleaning for the
// next graph replay; untouched entries are never modified).
__global__ __launch_bounds__(256)
void fused_bank(const float* __restrict__ f_out,
                const float* __restrict__ features,
                const int* __restrict__ labels,
                unsigned* __restrict__ first,
                unsigned* __restrict__ lastm,
                float* __restrict__ out) {
    const int y = blockIdx.x;
    const int tid = threadIdx.x;
    const floatx4* feat4 = reinterpret_cast<const floatx4*>(features);
    const float4* fout4 = reinterpret_cast<const float4*>(f_out);

    floatx4 v = __builtin_nontemporal_load(&feat4[(size_t)y * (NF / 4) + tid]);

    const unsigned h = first[y];       // block-uniform
    if (h < BATCH) {
        __shared__ float s_part[4];
        const unsigned lm = lastm[y];
        const unsigned last = BATCH - 1u - lm;   // huge if lm garbage >= BATCH
        // single-occurrence fast path: for labels truly present, atomicMin
        // guarantees h <= trueFirst and last >= trueLast, so h==last can only
        // happen at a genuine single occurrence; labels[h]==y rejects
        // absent-label garbage.
        if (h == last && labels[h] == (int)y) {
            blend_normalize(v, fout4[(size_t)h * (NF / 4) + tid], s_part, tid);
        } else {
            // self-computing path: collect all occurrences of y in batch order
            __shared__ int s_cnt;
            __shared__ int s_idx[MAXOCC];
            if (tid == 0) s_cnt = 0;
            __syncthreads();
            for (int j = tid; j < BATCH; j += 256) {
                if (labels[j] == y) {
                    const int p = atomicAdd(&s_cnt, 1);
                    if (p < MAXOCC) s_idx[p] = j;
                }
            }
            __syncthreads();
            const int n = min(s_cnt, MAXOCC);
            if (tid == 0) {            // insertion-sort tiny list ascending
                for (int a = 1; a < n; ++a) {
                    const int key = s_idx[a];
                    int b = a - 1;
                    while (b >= 0 && s_idx[b] > key) { s_idx[b + 1] = s_idx[b]; --b; }
                    s_idx[b + 1] = key;
                }
            }
            __syncthreads();
            for (int t = 0; t < n; ++t)
                blend_normalize(v, fout4[(size_t)s_idx[t] * (NF / 4) + tid],
                                s_part, tid);
        }
        if (tid == 0) {                // restore sentinel for next replay
            first[y] = SENT;
            lastm[y] = SENT;
        }
    }
    __builtin_nontemporal_store(v,
        &reinterpret_cast<floatx4*>(out)[(size_t)y * (NF / 4) + tid]);
}

extern "C" void kernel_launch(void* const* d_in, const int* in_sizes, int n_in,
                              void* d_out, int out_size, void* d_ws, size_t ws_size,
                              hipStream_t stream) {
    const float* f_out    = (const float*)d_in[0];
    const float* features = (const float*)d_in[1];
    const int*   labels   = (const int*)d_in[2];
    float* out = (float*)d_out;

    unsigned* first = (unsigned*)d_ws;   // NS unsigned
    unsigned* lastm = first + NS;        // NS unsigned

    build_firstlast<<<(BATCH + 255) / 256, 256, 0, stream>>>(labels, first, lastm);
    fused_bank<<<NS, 256, 0, stream>>>(f_out, features, labels, first, lastm, out);
}